// Round 1
// baseline (251.630 us; speedup 1.0000x reference)
//
#include <hip/hip_runtime.h>
#include <math.h>

// FastLearnableEMA: y[b,t,c] = cumsum_t(x * w) / max(a^t, 1e-8)
//   a = clamp(sigmoid(logit_alpha), 1e-4, 1-1e-4)      [C]
//   w[t] = a^t * (t==0 ? 1 : (1-a))
// B=32, T=2048, C=512, fp32 in/out. Memory-bound (268 MB min traffic).
//
// Block-local two-phase scan: block = 16 waves x 64 lanes covering
// (one b, 64 channels); wave w owns t-chunk [w*128, w*128+128).
// Phase 1: per-chunk weighted sums -> LDS. Phase 2: exclusive scan of
// chunk sums + re-scan emitting y (re-read hits Infinity Cache).

#define B_ 32
#define T_ 2048
#define C_ 512
#define WAVES 16
#define TCHUNK (T_ / WAVES)   // 128
#define CPB 64                // channels per block (one lane each)

__global__ __launch_bounds__(WAVES * 64, 1)
void ema_scan_kernel(const float* __restrict__ x,
                     const float* __restrict__ logit_alpha,
                     float* __restrict__ y) {
    __shared__ float csum[WAVES][CPB];   // 4 KB

    const int tid  = threadIdx.x;
    const int wave = tid >> 6;
    const int lane = tid & 63;
    const int b    = blockIdx.x >> 3;     // C_/CPB == 8 channel groups
    const int cg   = blockIdx.x & 7;
    const int c    = (cg << 6) + lane;

    // per-channel alpha (computed redundantly per wave; trivial cost)
    const float z = logit_alpha[c];
    float a = 1.0f / (1.0f + expf(-z));
    a = fminf(fmaxf(a, 1e-4f), 1.0f - 1e-4f);
    const float oma = 1.0f - a;

    const int t0 = wave * TCHUNK;
    const float l2a = log2f(a);
    const float ap0 = exp2f((float)t0 * l2a);     // a^t0 (0 if underflow — ok,
                                                  // those weights are <1e-38)

    const float* __restrict__ xp = x + ((size_t)b * T_ + t0) * C_ + c;
    float* __restrict__ yp       = y + ((size_t)b * T_ + t0) * C_ + c;

    // ---- phase 1: per-chunk weighted sum (last wave's sum is never consumed)
    if (wave < WAVES - 1) {
        float ap = ap0;
        float s  = 0.0f;
        #pragma unroll 8
        for (int i = 0; i < TCHUNK; ++i) {
            float w = (t0 + i == 0) ? 1.0f : ap * oma;
            s = fmaf(xp[(size_t)i * C_], w, s);
            ap *= a;
        }
        csum[wave][lane] = s;
    }
    __syncthreads();

    // ---- tiny exclusive scan of chunk sums (<=15 LDS reads/adds per lane)
    float S = 0.0f;
    for (int w2 = 0; w2 < wave; ++w2) S += csum[w2][lane];

    // ---- phase 2: re-scan chunk, emit y
    // 1/max(a^t,1e-8) == min(a^-t, 1e8): a^-t via recurrence; overflow->inf
    // is clamped to 1e8, matching the reference's EPS clamp exactly.
    float ap    = ap0;
    const float inva = 1.0f / a;
    float invap = exp2f(-(float)t0 * l2a);
    #pragma unroll 8
    for (int i = 0; i < TCHUNK; ++i) {
        float w = (t0 + i == 0) ? 1.0f : ap * oma;
        S = fmaf(xp[(size_t)i * C_], w, S);
        const float invd = fminf(invap, 1e8f);
        yp[(size_t)i * C_] = S * invd;
        ap    *= a;
        invap *= inva;
    }
}

extern "C" void kernel_launch(void* const* d_in, const int* in_sizes, int n_in,
                              void* d_out, int out_size, void* d_ws, size_t ws_size,
                              hipStream_t stream) {
    const float* x  = (const float*)d_in[0];   // [32, 2048, 512] fp32
    const float* la = (const float*)d_in[1];   // [512] fp32
    float* y = (float*)d_out;                  // [32, 2048, 512] fp32

    dim3 grid(B_ * (C_ / CPB));   // 256 blocks
    dim3 block(WAVES * 64);       // 1024 threads = 16 waves
    hipLaunchKernelGGL(ema_scan_kernel, grid, block, 0, stream, x, la, y);
}